// Round 3
// baseline (376.533 us; speedup 1.0000x reference)
//
#include <hip/hip_runtime.h>

typedef __attribute__((ext_vector_type(8))) short bf16x8;
typedef __attribute__((ext_vector_type(4))) float f32x4;

#define NWIN 4096     // 16^3 windows of 4^3

__device__ __forceinline__ unsigned short f2bf(float f) {
    unsigned int u = __float_as_uint(f);
    return (unsigned short)((u + 0x7FFFu + ((u >> 16) & 1u)) >> 16);
}
__device__ __forceinline__ float bf2f(unsigned short u) {
    return __uint_as_float(((unsigned int)u) << 16);
}
__device__ __forceinline__ int region(int g) { return (g >= 60) + (g >= 62); }

// ---------------- K0: weight convert + transpose to N-major bf16 ----------------
__global__ void convert_weights(const float* __restrict__ Wqkv, const float* __restrict__ Wout,
                                const float* __restrict__ W1, const float* __restrict__ W2,
                                unsigned short* __restrict__ wq_t, unsigned short* __restrict__ wo_t,
                                unsigned short* __restrict__ w1_t, unsigned short* __restrict__ w2_t) {
    int idx = blockIdx.x * blockDim.x + threadIdx.x;
    if (idx < 27648) {                       // wq_t[288][96] = Wqkv[96][288]^T
        int n = idx / 96, k = idx % 96;
        wq_t[idx] = f2bf(Wqkv[k * 288 + n]);
    } else if (idx < 27648 + 9216) {         // wo_t[96][96]
        int i = idx - 27648; int n = i / 96, k = i % 96;
        wo_t[i] = f2bf(Wout[k * 96 + n]);
    } else if (idx < 27648 + 9216 + 36864) { // w1_t[384][96]
        int i = idx - 36864; int n = i / 96, k = i % 96;
        w1_t[i] = f2bf(W1[k * 384 + n]);
    } else if (idx < 110592) {               // w2_t[96][384]
        int i = idx - 73728; int n = i / 384, k = i % 384;
        w2_t[i] = f2bf(W2[k * 96 + n]);
    }
}

// ---------------- K1: the whole Swin block, one workgroup per 4^3 window ----------------
// LDS plan (shorts; strides are multiples of 8 shorts so b128 frags stay 16B-aligned):
//  q_s  @0      [3][64][40]  (7680)   -> later aliased by ao [64][104] (6656)
//  k_s  @7680   [3][64][40]  (7680)   -> later aliased by xl [64][104] (6656)
//  vT   @15360  [3][32][72]  (6912)   -> later aliased by gl[0] (6656)
//  P_s  @22272  [3][64][72]  (13824)  -> y [64][104] early; gl[1] late
//  mu   @36096  (64 f32), rsd @36224 (64 f32), pos @36352 (344 f32)
// total 37040 shorts = 74080 B -> 2 blocks/CU.
__global__ __launch_bounds__(384, 3) void swin_mega(
    const float* __restrict__ x,
    const float* __restrict__ ln1_g, const float* __restrict__ ln1_b,
    const unsigned short* __restrict__ wq_t,
    const unsigned short* __restrict__ wo_t, const float* __restrict__ b_out,
    const float* __restrict__ pos_tab,
    const float* __restrict__ g2, const float* __restrict__ bt2,
    const unsigned short* __restrict__ w1_t, const float* __restrict__ b1,
    const unsigned short* __restrict__ w2_t, const float* __restrict__ b2,
    float* __restrict__ out)
{
    __shared__ __align__(16) unsigned short LDS[37040];
    unsigned short* q_s = LDS;            // [3][64][40]
    unsigned short* k_s = LDS + 7680;     // [3][64][40]
    unsigned short* vT  = LDS + 15360;    // [3][32][72]
    unsigned short* P_s = LDS + 22272;    // [3][64][72]
    unsigned short* y_s = LDS + 22272;    // [64][104]  (aliases P_s, dead before P written)
    unsigned short* ao  = LDS;            // [64][104]  (aliases q_s, written after q dead)
    unsigned short* xl  = LDS + 7680;     // [64][104]  (aliases k_s)
    unsigned short* gl0 = LDS + 15360;    // gl[b] = gl0 + b*6656 (aliases vT/P, dead then)
    float* mu   = (float*)(LDS + 36096);
    float* rsd  = (float*)(LDS + 36224);
    float* posl = (float*)(LDS + 36352);

    int win = blockIdx.x;
    int tid = threadIdx.x;
    int w = tid >> 6, lane = tid & 63, lr = lane & 15, kh = lane >> 4;
    int ix = win >> 8, iy = (win >> 4) & 15, iz = win & 15;

    if (tid < 343) posl[tid] = pos_tab[tid];

    // ---- P1: LN1 on shifted-gathered window tokens -> y_s (bf16) ----
    {
        int grp = tid >> 4, gi = tid & 15;
        float gv[6], bv[6];
        #pragma unroll
        for (int j = 0; j < 6; ++j) { gv[j] = ln1_g[gi + 16 * j]; bv[j] = ln1_b[gi + 16 * j]; }
        #pragma unroll
        for (int p = 0; p < 3; ++p) {
            int t = grp + p * 24;
            if (t < 64) {
                int wx = t >> 4, wy = (t >> 2) & 3, wz = t & 3;
                int sx = (ix * 4 + wx + 2) & 63, sy = (iy * 4 + wy + 2) & 63, sz = (iz * 4 + wz + 2) & 63;
                const float* src = x + ((size_t)((sx * 64 + sy) * 64 + sz)) * 96;
                float v[6]; float s = 0.f, sq = 0.f;
                #pragma unroll
                for (int j = 0; j < 6; ++j) { v[j] = src[gi + 16 * j]; s += v[j]; sq += v[j] * v[j]; }
                #pragma unroll
                for (int m = 8; m >= 1; m >>= 1) { s += __shfl_xor(s, m, 16); sq += __shfl_xor(sq, m, 16); }
                float mean = s * (1.0f / 96.0f);
                float var = sq * (1.0f / 96.0f) - mean * mean;
                float rstd = rsqrtf(var + 1e-5f);
                #pragma unroll
                for (int j = 0; j < 6; ++j)
                    y_s[t * 104 + gi + 16 * j] = f2bf((v[j] - mean) * rstd * gv[j] + bv[j]);
            }
        }
    }
    __syncthreads();

    // ---- P2: QKV GEMM (A = y_s, B = wq_t from L2); scatter to q_s (pre-scaled), k_s, vT ----
    {
        f32x4 acc3[4][3];
        #pragma unroll
        for (int m = 0; m < 4; ++m)
            #pragma unroll
            for (int n = 0; n < 3; ++n) acc3[m][n] = (f32x4){0.f, 0.f, 0.f, 0.f};
        #pragma unroll
        for (int ks = 0; ks < 3; ++ks) {
            int k0 = ks * 32;
            bf16x8 a[4], bb[3];
            #pragma unroll
            for (int m = 0; m < 4; ++m)
                a[m] = *(const bf16x8*)&y_s[(m * 16 + lr) * 104 + k0 + kh * 8];
            #pragma unroll
            for (int n = 0; n < 3; ++n)
                bb[n] = *(const bf16x8*)(wq_t + (size_t)(w * 48 + n * 16 + lr) * 96 + k0 + kh * 8);
            #pragma unroll
            for (int m = 0; m < 4; ++m)
                #pragma unroll
                for (int n = 0; n < 3; ++n)
                    acc3[m][n] = __builtin_amdgcn_mfma_f32_16x16x32_bf16(a[m], bb[n], acc3[m][n], 0, 0, 0);
        }
        const float scale = 0.17677669529663689f;   // 32^-0.5 folded into Q
        #pragma unroll
        for (int n = 0; n < 3; ++n) {
            int base = w * 48 + n * 16;
            int qq = base / 96, cc0 = base % 96;
            int hh = cc0 >> 5, d0 = cc0 & 31;
            #pragma unroll
            for (int m = 0; m < 4; ++m)
                #pragma unroll
                for (int r = 0; r < 4; ++r) {
                    int tok = m * 16 + kh * 4 + r;
                    float val = acc3[m][n][r];
                    if (qq == 0)      q_s[(hh * 64 + tok) * 40 + d0 + lr] = f2bf(val * scale);
                    else if (qq == 1) k_s[(hh * 64 + tok) * 40 + d0 + lr] = f2bf(val);
                    else              vT[(hh * 32 + d0 + lr) * 72 + tok] = f2bf(val);
                }
        }
    }
    __syncthreads();

    // ---- P3: QK^T + bias + mask + softmax -> P_s (2 waves per head) ----
    int h3 = w >> 1, rb = (w & 1) * 32;
    {
        bf16x8 aq[2], bk[4];
        #pragma unroll
        for (int mm = 0; mm < 2; ++mm)
            aq[mm] = *(const bf16x8*)&q_s[(h3 * 64 + rb + mm * 16 + lr) * 40 + kh * 8];
        #pragma unroll
        for (int n = 0; n < 4; ++n)
            bk[n] = *(const bf16x8*)&k_s[(h3 * 64 + n * 16 + lr) * 40 + kh * 8];
        f32x4 sa[2][4];
        #pragma unroll
        for (int mm = 0; mm < 2; ++mm)
            #pragma unroll
            for (int n = 0; n < 4; ++n)
                sa[mm][n] = __builtin_amdgcn_mfma_f32_16x16x32_bf16(aq[mm], bk[n], (f32x4){0.f,0.f,0.f,0.f}, 0, 0, 0);

        int labj[4], jwx[4], jwy[4], jwz[4];
        #pragma unroll
        for (int n = 0; n < 4; ++n) {
            int j = n * 16 + lr;
            jwx[n] = j >> 4; jwy[n] = (j >> 2) & 3; jwz[n] = j & 3;
            labj[n] = 9 * region(ix * 4 + jwx[n]) + 3 * region(iy * 4 + jwy[n]) + region(iz * 4 + jwz[n]);
        }
        #pragma unroll
        for (int mm = 0; mm < 2; ++mm)
            #pragma unroll
            for (int r = 0; r < 4; ++r) {
                int i = rb + mm * 16 + kh * 4 + r;
                int iwx = i >> 4, iwy = (i >> 2) & 3, iwz = i & 3;
                int labi = 9 * region(ix * 4 + iwx) + 3 * region(iy * 4 + iwy) + region(iz * 4 + iwz);
                #pragma unroll
                for (int n = 0; n < 4; ++n) {
                    float bias = posl[((iwx - jwx[n] + 3) * 7 + (iwy - jwy[n] + 3)) * 7 + (iwz - jwz[n] + 3)];
                    sa[mm][n][r] += bias + (labi != labj[n] ? -1e9f : 0.0f);
                }
                // softmax over the 64-wide row (4 n-frags x 16 lanes)
                float mx = fmaxf(fmaxf(sa[0][0][r], 0.f), 0.f); // placeholder overwritten below
                mx = fmaxf(fmaxf(sa[mm][0][r], sa[mm][1][r]), fmaxf(sa[mm][2][r], sa[mm][3][r]));
                #pragma unroll
                for (int s = 1; s < 16; s <<= 1) mx = fmaxf(mx, __shfl_xor(mx, s, 16));
                float e0 = __expf(sa[mm][0][r] - mx), e1 = __expf(sa[mm][1][r] - mx);
                float e2 = __expf(sa[mm][2][r] - mx), e3 = __expf(sa[mm][3][r] - mx);
                float sum = e0 + e1 + e2 + e3;
                #pragma unroll
                for (int s = 1; s < 16; s <<= 1) sum += __shfl_xor(sum, s, 16);
                float rs = 1.0f / sum;
                sa[mm][0][r] = e0 * rs; sa[mm][1][r] = e1 * rs;
                sa[mm][2][r] = e2 * rs; sa[mm][3][r] = e3 * rs;
            }
        #pragma unroll
        for (int mm = 0; mm < 2; ++mm)
            #pragma unroll
            for (int n = 0; n < 4; ++n)
                #pragma unroll
                for (int r = 0; r < 4; ++r)
                    P_s[(h3 * 64 + rb + mm * 16 + kh * 4 + r) * 72 + n * 16 + lr] = f2bf(sa[mm][n][r]);
    }
    __syncthreads();

    // ---- P4: PV -> ao (aliases q_s) ----
    {
        f32x4 oa[2][2];
        #pragma unroll
        for (int mm = 0; mm < 2; ++mm)
            #pragma unroll
            for (int n = 0; n < 2; ++n) oa[mm][n] = (f32x4){0.f, 0.f, 0.f, 0.f};
        #pragma unroll
        for (int ks = 0; ks < 2; ++ks) {
            int k0 = ks * 32;
            bf16x8 ap[2], bv[2];
            #pragma unroll
            for (int mm = 0; mm < 2; ++mm)
                ap[mm] = *(const bf16x8*)&P_s[(h3 * 64 + rb + mm * 16 + lr) * 72 + k0 + kh * 8];
            #pragma unroll
            for (int n = 0; n < 2; ++n)
                bv[n] = *(const bf16x8*)&vT[(h3 * 32 + n * 16 + lr) * 72 + k0 + kh * 8];
            #pragma unroll
            for (int mm = 0; mm < 2; ++mm)
                #pragma unroll
                for (int n = 0; n < 2; ++n)
                    oa[mm][n] = __builtin_amdgcn_mfma_f32_16x16x32_bf16(ap[mm], bv[n], oa[mm][n], 0, 0, 0);
        }
        __syncthreads();   // q_s reads (P3) done everywhere before ao overwrites it
        #pragma unroll
        for (int mm = 0; mm < 2; ++mm)
            #pragma unroll
            for (int n = 0; n < 2; ++n)
                #pragma unroll
                for (int r = 0; r < 4; ++r) {
                    int tok = rb + mm * 16 + kh * 4 + r;
                    ao[tok * 104 + h3 * 32 + n * 16 + lr] = f2bf(oa[mm][n][r]);
                }
    }
    __syncthreads();

    // ---- P5: out-proj + f32 residual (kept in regs) ; write bf16 x1 -> xl ----
    int c = w * 16 + lr;
    float x1r[4][4];
    {
        f32x4 pacc[4];
        #pragma unroll
        for (int m = 0; m < 4; ++m) pacc[m] = (f32x4){0.f, 0.f, 0.f, 0.f};
        #pragma unroll
        for (int ks = 0; ks < 3; ++ks) {
            int k0 = ks * 32;
            bf16x8 bb = *(const bf16x8*)(wo_t + (size_t)c * 96 + k0 + kh * 8);
            #pragma unroll
            for (int m = 0; m < 4; ++m) {
                bf16x8 a = *(const bf16x8*)&ao[(m * 16 + lr) * 104 + k0 + kh * 8];
                pacc[m] = __builtin_amdgcn_mfma_f32_16x16x32_bf16(a, bb, pacc[m], 0, 0, 0);
            }
        }
        float bo = b_out[c];
        #pragma unroll
        for (int m = 0; m < 4; ++m)
            #pragma unroll
            for (int r = 0; r < 4; ++r) {
                int tok = m * 16 + kh * 4 + r;
                int wx = tok >> 4, wy = (tok >> 2) & 3, wz = tok & 3;
                int px = (ix * 4 + wx + 2) & 63, py = (iy * 4 + wy + 2) & 63, pz = (iz * 4 + wz + 2) & 63;
                size_t o = ((size_t)((px * 64 + py) * 64 + pz)) * 96 + c;
                x1r[m][r] = x[o] + pacc[m][r] + bo;     // same addresses P1 streamed -> L3 hit
                xl[tok * 104 + c] = f2bf(x1r[m][r]);
            }
    }
    __syncthreads();

    // ---- P6: LN2 stats from xl -> mu / rsd ----
    {
        int grp = tid >> 4, gi = tid & 15;
        #pragma unroll
        for (int p = 0; p < 3; ++p) {
            int t = grp + p * 24;
            if (t < 64) {
                float s = 0.f, sq = 0.f;
                #pragma unroll
                for (int j = 0; j < 6; ++j) {
                    float v = bf2f(xl[t * 104 + gi + 16 * j]);
                    s += v; sq += v * v;
                }
                #pragma unroll
                for (int m = 8; m >= 1; m >>= 1) { s += __shfl_xor(s, m, 16); sq += __shfl_xor(sq, m, 16); }
                if (gi == 0) {
                    float mean = s * (1.0f / 96.0f);
                    float var = sq * (1.0f / 96.0f) - mean * mean;
                    mu[t] = mean; rsd[t] = rsqrtf(var + 1e-5f);
                }
            }
        }
    }
    __syncthreads();

    // ---- P7: normalize xl in place (each thread owns its 16 slots) ----
    {
        float gc = g2[c], bc = bt2[c];
        #pragma unroll
        for (int m = 0; m < 4; ++m)
            #pragma unroll
            for (int r = 0; r < 4; ++r) {
                int tok = m * 16 + kh * 4 + r;
                float v = bf2f(xl[tok * 104 + c]);
                xl[tok * 104 + c] = f2bf((v - mu[tok]) * rsd[tok] * gc + bc);
            }
    }
    __syncthreads();

    // ---- P8: MLP, hidden dim in 4 chunks of 96, double-buffered gl ----
    int wm = w & 1, wn = w >> 1;
    f32x4 acc2[4];
    #pragma unroll
    for (int m = 0; m < 4; ++m) acc2[m] = (f32x4){0.f, 0.f, 0.f, 0.f};

    auto G1c = [&](int ch, f32x4 (&a1)[2][2]) {
        #pragma unroll
        for (int mf = 0; mf < 2; ++mf)
            #pragma unroll
            for (int nf = 0; nf < 2; ++nf) a1[mf][nf] = (f32x4){0.f, 0.f, 0.f, 0.f};
        #pragma unroll
        for (int ks = 0; ks < 3; ++ks) {
            int k0 = ks * 32;
            bf16x8 af[2], bfr[2];
            #pragma unroll
            for (int mf = 0; mf < 2; ++mf)
                af[mf] = *(const bf16x8*)&xl[(wm * 32 + mf * 16 + lr) * 104 + k0 + kh * 8];
            #pragma unroll
            for (int nf = 0; nf < 2; ++nf)
                bfr[nf] = *(const bf16x8*)(w1_t + (size_t)(ch * 96 + wn * 32 + nf * 16 + lr) * 96 + k0 + kh * 8);
            #pragma unroll
            for (int mf = 0; mf < 2; ++mf)
                #pragma unroll
                for (int nf = 0; nf < 2; ++nf)
                    a1[mf][nf] = __builtin_amdgcn_mfma_f32_16x16x32_bf16(af[mf], bfr[nf], a1[mf][nf], 0, 0, 0);
        }
    };
    auto GST = [&](int ch, f32x4 (&a1)[2][2]) {
        unsigned short* glb = gl0 + (ch & 1) * 6656;
        #pragma unroll
        for (int nf = 0; nf < 2; ++nf) {
            int col = wn * 32 + nf * 16 + lr;
            float bias = b1[ch * 96 + col];
            #pragma unroll
            for (int mf = 0; mf < 2; ++mf)
                #pragma unroll
                for (int r = 0; r < 4; ++r) {
                    float u = a1[mf][nf][r] + bias;
                    // gelu ~= u * sigmoid(1.5957691216*(u + 0.044715 u^3)); |err| < 3e-3
                    float t = 1.5957691216057308f * (u + 0.044715f * u * u * u);
                    float ge = u / (1.0f + __expf(-t));
                    glb[(wm * 32 + mf * 16 + kh * 4 + r) * 104 + col] = f2bf(ge);
                }
        }
    };
    auto G2c = [&](int ch) {
        const unsigned short* glb = gl0 + (ch & 1) * 6656;
        #pragma unroll
        for (int kc = 0; kc < 3; ++kc) {
            int k0 = kc * 32;
            bf16x8 bb = *(const bf16x8*)(w2_t + (size_t)c * 384 + ch * 96 + k0 + kh * 8);
            #pragma unroll
            for (int m = 0; m < 4; ++m) {
                bf16x8 a = *(const bf16x8*)&glb[(m * 16 + lr) * 104 + k0 + kh * 8];
                acc2[m] = __builtin_amdgcn_mfma_f32_16x16x32_bf16(a, bb, acc2[m], 0, 0, 0);
            }
        }
    };

    {
        f32x4 a1[2][2];
        G1c(0, a1); GST(0, a1);
        __syncthreads();
        for (int ch = 0; ch < 4; ++ch) {
            f32x4 nx[2][2];
            if (ch < 3) G1c(ch + 1, nx);
            G2c(ch);
            if (ch < 3) { GST(ch + 1, nx); __syncthreads(); }
        }
    }

    // ---- P9: final residual write (x1 kept f32 in registers) ----
    {
        float b2c = b2[c];
        #pragma unroll
        for (int m = 0; m < 4; ++m)
            #pragma unroll
            for (int r = 0; r < 4; ++r) {
                int tok = m * 16 + kh * 4 + r;
                int wx = tok >> 4, wy = (tok >> 2) & 3, wz = tok & 3;
                int px = (ix * 4 + wx + 2) & 63, py = (iy * 4 + wy + 2) & 63, pz = (iz * 4 + wz + 2) & 63;
                size_t o = ((size_t)((px * 64 + py) * 64 + pz)) * 96 + c;
                out[o] = x1r[m][r] + acc2[m][r] + b2c;
            }
    }
}

extern "C" void kernel_launch(void* const* d_in, const int* in_sizes, int n_in,
                              void* d_out, int out_size, void* d_ws, size_t ws_size,
                              hipStream_t stream) {
    const float* x       = (const float*)d_in[0];
    const float* Wqkv    = (const float*)d_in[1];
    const float* Wout    = (const float*)d_in[2];
    const float* b_out   = (const float*)d_in[3];
    const float* pos_tab = (const float*)d_in[4];
    const float* ln1_g   = (const float*)d_in[5];
    const float* ln1_b   = (const float*)d_in[6];
    const float* ln2_g   = (const float*)d_in[7];
    const float* ln2_b   = (const float*)d_in[8];
    const float* W1      = (const float*)d_in[9];
    const float* b1      = (const float*)d_in[10];
    const float* W2      = (const float*)d_in[11];
    const float* b2      = (const float*)d_in[12];
    float* out = (float*)d_out;

    unsigned short* wq_t = (unsigned short*)d_ws;    // [288][96]
    unsigned short* wo_t = wq_t + 27648;             // [96][96]
    unsigned short* w1_t = wo_t + 9216;              // [384][96]
    unsigned short* w2_t = w1_t + 36864;             // [96][384]

    convert_weights<<<432, 256, 0, stream>>>(Wqkv, Wout, W1, W2, wq_t, wo_t, w1_t, w2_t);
    swin_mega<<<NWIN, 384, 0, stream>>>(x, ln1_g, ln1_b, wq_t, wo_t, b_out, pos_tab,
                                        ln2_g, ln2_b, w1_t, b1, w2_t, b2, out);
}